// Round 1
// baseline (158.879 us; speedup 1.0000x reference)
//
#include <hip/hip_runtime.h>

typedef _Float16 half8_t __attribute__((ext_vector_type(8)));
typedef _Float16 half4_t __attribute__((ext_vector_type(4)));
typedef float    float4_t __attribute__((ext_vector_type(4)));

#define N_TILES 1024
#define PTS     256
#define IN_F    256
#define OUT_F   256
#define BK      32
#define LDK     40          // BK + 8 fp16 pad (16B) -> aligned ds_read_b128, conflict-free
#define NSTEP   (IN_F / BK) // 8
#define OMEGA_C 30.0f

// One block per tile: C[256x256] = sin(OMEGA * (X[256x256] @ W[ch][256x256] + bias))
// 512 threads = 8 waves in a 2(M) x 4(N) grid; per-wave 128x64 output = acc[8][4] f32x4.
// fp16 inputs, fp32 MFMA accumulate (error ~4e-3 << 2e-2 threshold).
__global__ __launch_bounds__(512, 2)
void siren_tile_gemm(const float* __restrict__ x,
                     const float* __restrict__ w,
                     const float* __restrict__ bias,
                     const void* __restrict__ idx_raw,
                     float* __restrict__ out) {
  __shared__ __align__(16) _Float16 Al[2][PTS][LDK];   // 40 KB
  __shared__ __align__(16) _Float16 Bl[2][OUT_F][LDK]; // 40 KB (transposed: [n][k])
  __shared__ int s_is32;

  const int tid  = threadIdx.x;
  const int tile = blockIdx.x;

  // ---- indices dtype self-detect (int64 per reference, but JAX may demote to int32) ----
  if (tid == 0) s_is32 = 0;
  __syncthreads();
  // If the buffer is int64, every hi-word of the first 512 entries is 0 (values < 1024).
  // If it is int32, the "hi-words" are real random indices -> some nonzero almost surely.
  if (((const int*)idx_raw)[2 * tid + 1] != 0) atomicOr(&s_is32, 1);
  __syncthreads();
  const int ch = s_is32 ? ((const int*)idx_raw)[tile]
                        : (int)(((const long long*)idx_raw)[tile]);

  const float* __restrict__ Xg = x + (size_t)tile * (PTS * IN_F);
  const float* __restrict__ Wg = w + (size_t)ch * (IN_F * OUT_F);

  // A staging: pass p in 0..3: row = p*64 + (tid>>3), 8 threads x float4 cover one row's 32 k
  const int a_row = tid >> 3; // 0..63
  const int a_lir = tid & 7;  // 0..7
  // B staging: wave-sized row reads: kb = tid>>6 (0..7), nb = tid&63; 4x4 register transpose
  const int b_kb = tid >> 6;
  const int b_nb = tid & 63;

  float4_t acc[8][4];
#pragma unroll
  for (int m = 0; m < 8; ++m)
#pragma unroll
    for (int n = 0; n < 4; ++n)
      acc[m][n] = (float4_t){0.f, 0.f, 0.f, 0.f};

  float4_t a_ld[4], b_ld[4];

  // ---- prologue: stage k-step 0 into buffer 0 ----
#pragma unroll
  for (int p = 0; p < 4; ++p)
    a_ld[p] = *(const float4_t*)(Xg + (size_t)(a_row + 64 * p) * IN_F + a_lir * 4);
#pragma unroll
  for (int j = 0; j < 4; ++j)
    b_ld[j] = *(const float4_t*)(Wg + (size_t)(b_kb * 4 + j) * OUT_F + b_nb * 4);
#pragma unroll
  for (int p = 0; p < 4; ++p) {
    half4_t h = {(_Float16)a_ld[p].x, (_Float16)a_ld[p].y,
                 (_Float16)a_ld[p].z, (_Float16)a_ld[p].w};
    *(half4_t*)&Al[0][a_row + 64 * p][a_lir * 4] = h;
  }
#pragma unroll
  for (int i = 0; i < 4; ++i) {
    half4_t h = {(_Float16)b_ld[0][i], (_Float16)b_ld[1][i],
                 (_Float16)b_ld[2][i], (_Float16)b_ld[3][i]};
    *(half4_t*)&Bl[0][b_nb * 4 + i][b_kb * 4] = h;
  }
  __syncthreads();

  const int wid  = tid >> 6;
  const int lane = tid & 63;
  const int mrow = (wid >> 2) * 128; // wave M origin
  const int ncol = (wid & 3) * 64;   // wave N origin
  const int fr   = lane & 15;        // fragment row/col
  const int kg   = lane >> 4;        // k-group (8 contiguous fp16)

  // ---- main loop: issue next loads early, MFMA current, convert+write late (T14) ----
#pragma unroll 2
  for (int s = 0; s < NSTEP; ++s) {
    const int cur = s & 1;
    if (s + 1 < NSTEP) {
      const int k0 = (s + 1) * BK;
#pragma unroll
      for (int p = 0; p < 4; ++p)
        a_ld[p] = *(const float4_t*)(Xg + (size_t)(a_row + 64 * p) * IN_F + k0 + a_lir * 4);
#pragma unroll
      for (int j = 0; j < 4; ++j)
        b_ld[j] = *(const float4_t*)(Wg + (size_t)(k0 + b_kb * 4 + j) * OUT_F + b_nb * 4);
    }

    half8_t af[8], bf[4];
#pragma unroll
    for (int m = 0; m < 8; ++m)
      af[m] = *(const half8_t*)&Al[cur][mrow + m * 16 + fr][kg * 8];
#pragma unroll
    for (int n = 0; n < 4; ++n)
      bf[n] = *(const half8_t*)&Bl[cur][ncol + n * 16 + fr][kg * 8];

#pragma unroll
    for (int m = 0; m < 8; ++m)
#pragma unroll
      for (int n = 0; n < 4; ++n)
        acc[m][n] = __builtin_amdgcn_mfma_f32_16x16x32_f16(af[m], bf[n], acc[m][n], 0, 0, 0);

    if (s + 1 < NSTEP) {
      const int nxt = cur ^ 1;
#pragma unroll
      for (int p = 0; p < 4; ++p) {
        half4_t h = {(_Float16)a_ld[p].x, (_Float16)a_ld[p].y,
                     (_Float16)a_ld[p].z, (_Float16)a_ld[p].w};
        *(half4_t*)&Al[nxt][a_row + 64 * p][a_lir * 4] = h;
      }
#pragma unroll
      for (int i = 0; i < 4; ++i) {
        half4_t h = {(_Float16)b_ld[0][i], (_Float16)b_ld[1][i],
                     (_Float16)b_ld[2][i], (_Float16)b_ld[3][i]};
        *(half4_t*)&Bl[nxt][b_nb * 4 + i][b_kb * 4] = h;
      }
    }
    __syncthreads();
  }

  // ---- epilogue: bias + sin, scalar f32 stores (C/D layout: col=lane&15, row=(lane>>4)*4+j) ----
  float bv[4];
#pragma unroll
  for (int n = 0; n < 4; ++n) bv[n] = bias[ncol + n * 16 + fr];

  float* __restrict__ Og = out + (size_t)tile * (PTS * OUT_F);
#pragma unroll
  for (int m = 0; m < 8; ++m) {
#pragma unroll
    for (int n = 0; n < 4; ++n) {
#pragma unroll
      for (int j = 0; j < 4; ++j) {
        const int row = mrow + m * 16 + kg * 4 + j;
        const int col = ncol + n * 16 + fr;
        Og[(size_t)row * OUT_F + col] = __sinf(OMEGA_C * (acc[m][n][j] + bv[n]));
      }
    }
  }
}

extern "C" void kernel_launch(void* const* d_in, const int* in_sizes, int n_in,
                              void* d_out, int out_size, void* d_ws, size_t ws_size,
                              hipStream_t stream) {
  const float* x    = (const float*)d_in[0];
  const float* w    = (const float*)d_in[1];
  const float* bias = (const float*)d_in[2];
  const void*  idx  = d_in[3];
  float*       out  = (float*)d_out;

  siren_tile_gemm<<<N_TILES, 512, 0, stream>>>(x, w, bias, idx, out);
}